// Round 3
// baseline (80.796 us; speedup 1.0000x reference)
//
#include <hip/hip_runtime.h>
#include <math.h>

// Quantum circuit collapses to z_q[b] = x^T K_q y with
//   x = [1, cos(pi*n0), sin(pi*n0)],  y = [1, cos(pi*n1), sin(pi*n1)],
// where K_q (9 floats per wire) depends only on q_weights.
// Derivation: z_q = r^T A_q r, r = kron([c0,s0],[c1,s1]); the Kronecker
// structure folds symmetric A_q into a 3x3 bilinear form over the moment
// vectors [c^2, c s, s^2]; double-angle maps those to [1, C, S]/2.
//
// Single dispatch: lane 0 of each 256-thread block computes K with native
// trig (~600 serial cycles), 4-wave barrier, 8 resident blocks/CU hide each
// other's prep. Main loop: 8 trans + ~40 FMA per float4 (2 samples) --
// memory-bound by ~5x, so it rides the HBM roofline.

struct Cx { float re, im; };
__device__ inline Cx cmul(Cx a, Cx b){ return {a.re*b.re - a.im*b.im, a.re*b.im + a.im*b.re}; }
__device__ inline Cx cmadd2(Cx a, Cx x, Cx b, Cx y){
  Cx p = cmul(a,x), q = cmul(b,y);
  return { p.re + q.re, p.im + q.im };
}

__device__ void compute_K(const float* __restrict__ w, float* __restrict__ K) {
  Cx U[4][4];
  #pragma unroll
  for (int r = 0; r < 4; ++r)
    #pragma unroll
    for (int c = 0; c < 4; ++c)
      U[r][c] = { (r == c) ? 1.f : 0.f, 0.f };

  #pragma unroll
  for (int l = 0; l < 2; ++l) {
    Cx g[2][2][2];  // [wire][i][j]
    #pragma unroll
    for (int q = 0; q < 2; ++q) {
      float phi = w[l*6 + q*3 + 0];
      float th  = w[l*6 + q*3 + 1];
      float om  = w[l*6 + q*3 + 2];
      float st, ct; __sincosf(0.5f*th, &st, &ct);        // native trig: args
      float sp, cp; __sincosf(0.5f*(phi+om), &sp, &cp);  // ~0.1 rad, precision
      float sm, cm; __sincosf(0.5f*(phi-om), &sm, &cm);  // ample at 4e-3 tol
      g[q][0][0] = {  cp*ct, -sp*ct };
      g[q][0][1] = { -cm*st, -sm*st };
      g[q][1][0] = {  cm*st, -sm*st };
      g[q][1][1] = {  cp*ct,  sp*ct };
    }
    // U <- (g0 (x) I) * U   (basis idx = 2*q0 + q1; mixes q0)
    #pragma unroll
    for (int c = 0; c < 4; ++c)
      #pragma unroll
      for (int k = 0; k < 2; ++k) {
        Cx x0 = U[k][c], x1 = U[2+k][c];
        U[k][c]   = cmadd2(g[0][0][0], x0, g[0][0][1], x1);
        U[2+k][c] = cmadd2(g[0][1][0], x0, g[0][1][1], x1);
      }
    // U <- (I (x) g1) * U   (mixes q1)
    #pragma unroll
    for (int c = 0; c < 4; ++c)
      #pragma unroll
      for (int j = 0; j < 2; ++j) {
        Cx x0 = U[2*j][c], x1 = U[2*j+1][c];
        U[2*j][c]   = cmadd2(g[1][0][0], x0, g[1][0][1], x1);
        U[2*j+1][c] = cmadd2(g[1][1][0], x0, g[1][1][1], x1);
      }
    // CNOT(q0->q1): swap rows 2,3 ; CNOT(q1->q0): swap rows 1,3
    #pragma unroll
    for (int c = 0; c < 4; ++c) { Cx t = U[2][c]; U[2][c] = U[3][c]; U[3][c] = t; }
    #pragma unroll
    for (int c = 0; c < 4; ++c) { Cx t = U[1][c]; U[1][c] = U[3][c]; U[3][c] = t; }
  }

  // V = U * D, D = diag(1, -i, -i, -1)
  #pragma unroll
  for (int r = 0; r < 4; ++r) {
    Cx t;
    t = U[r][1]; U[r][1] = {  t.im, -t.re };
    t = U[r][2]; U[r][2] = {  t.im, -t.re };
    t = U[r][3]; U[r][3] = { -t.re, -t.im };
  }

  // A_q[a][b] = sum_r zq[r] * Re( conj(V[r][a]) V[r][b] )   (symmetric)
  const float z0s[4] = { 1.f,  1.f, -1.f, -1.f };
  const float z1s[4] = { 1.f, -1.f,  1.f, -1.f };
  float A[2][16];
  #pragma unroll
  for (int a = 0; a < 4; ++a)
    #pragma unroll
    for (int b = 0; b < 4; ++b) {
      float a0 = 0.f, a1 = 0.f;
      #pragma unroll
      for (int r = 0; r < 4; ++r) {
        float d = U[r][a].re*U[r][b].re + U[r][a].im*U[r][b].im;
        a0 += z0s[r]*d;
        a1 += z1s[r]*d;
      }
      A[0][a*4 + b] = a0;
      A[1][a*4 + b] = a1;
    }

  // Fold Kronecker structure: z = sum_{a,b in 0..2} M[a][b] u_a v_b,
  //   u = [c0^2, c0 s0, s0^2], v likewise (off-diagonals of A appear twice)
  // then basis change [c^2, c s, s^2] = T [1, C, S]^T, K = T^T (M T).
  const float T[3][3] = { {0.5f, 0.5f, 0.f},
                          {0.f,  0.f,  0.5f},
                          {0.5f, -0.5f, 0.f} };
  #pragma unroll
  for (int q = 0; q < 2; ++q) {
    const float* a = A[q];
    float M[9];
    M[0] = a[0];
    M[1] = 2.f*a[1];
    M[2] = a[5];
    M[3] = 2.f*a[2];
    M[4] = 2.f*(a[3]+a[6]);
    M[5] = 2.f*a[7];
    M[6] = a[10];
    M[7] = 2.f*a[11];
    M[8] = a[15];
    float tmp[9];  // tmp = M * T
    #pragma unroll
    for (int r = 0; r < 3; ++r)
      #pragma unroll
      for (int d = 0; d < 3; ++d)
        tmp[r*3+d] = M[r*3+0]*T[0][d] + M[r*3+1]*T[1][d] + M[r*3+2]*T[2][d];
    #pragma unroll
    for (int c = 0; c < 3; ++c)    // K = T^T * tmp
      #pragma unroll
      for (int d = 0; d < 3; ++d)
        K[q*9 + c*3 + d] = T[0][c]*tmp[0*3+d] + T[1][c]*tmp[1*3+d] + T[2][c]*tmp[2*3+d];
  }
}

__device__ inline float evalK(const float* __restrict__ k,
                              float C0, float S0, float C1, float S1) {
  float t0 = fmaf(k[2], S1, fmaf(k[1], C1, k[0]));
  float t1 = fmaf(k[5], S1, fmaf(k[4], C1, k[3]));
  float t2 = fmaf(k[8], S1, fmaf(k[7], C1, k[6]));
  return fmaf(S0, t2, fmaf(C0, t1, t0));
}

__global__ __launch_bounds__(256) void qc_fused(const float* __restrict__ noise,
                                                const float* __restrict__ w,
                                                float* __restrict__ out,
                                                int nQuads) {
  __shared__ float sK[18];

  const float4* __restrict__ in4  = (const float4*)noise;
  float4* __restrict__ out4 = (float4*)out;

  int i = blockIdx.x * blockDim.x + threadIdx.x;
  bool valid = (i < nQuads);

  // Issue the input load BEFORE the prep/barrier: HBM latency covers the
  // lane-0 prep chain; only 4 waves wait at this barrier.
  float4 v = {0.f, 0.f, 0.f, 0.f};
  if (valid) v = in4[i];

  if (threadIdx.x == 0) compute_K(w, sK);
  __syncthreads();

  float k0[9], k1[9];
  #pragma unroll
  for (int j = 0; j < 9; ++j) { k0[j] = sK[j]; k1[j] = sK[9 + j]; }  // broadcast

  if (!valid) return;

  // v_sin/v_cos take revolutions: cos(pi*n) = v_cos(0.5*n); n in [0,1) needs
  // no range reduction.
  float4 o;
  {
    float C0 = __builtin_amdgcn_cosf(0.5f * v.x);
    float S0 = __builtin_amdgcn_sinf(0.5f * v.x);
    float C1 = __builtin_amdgcn_cosf(0.5f * v.y);
    float S1 = __builtin_amdgcn_sinf(0.5f * v.y);
    o.x = evalK(k0, C0, S0, C1, S1);
    o.y = evalK(k1, C0, S0, C1, S1);
  }
  {
    float C0 = __builtin_amdgcn_cosf(0.5f * v.z);
    float S0 = __builtin_amdgcn_sinf(0.5f * v.z);
    float C1 = __builtin_amdgcn_cosf(0.5f * v.w);
    float S1 = __builtin_amdgcn_sinf(0.5f * v.w);
    o.z = evalK(k0, C0, S0, C1, S1);
    o.w = evalK(k1, C0, S0, C1, S1);
  }
  out4[i] = o;
}

extern "C" void kernel_launch(void* const* d_in, const int* in_sizes, int n_in,
                              void* d_out, int out_size, void* d_ws, size_t ws_size,
                              hipStream_t stream) {
  const float* noise = (const float*)d_in[0];   // [B,2] float32
  const float* w     = (const float*)d_in[1];   // [2,2,3] float32
  float* out         = (float*)d_out;           // [B,2] float32

  int nQuads  = in_sizes[0] / 4;                // (B*2 floats)/4 -> float4 count
  int threads = 256;                            // 4-wave blocks: cheap barrier,
  int blocks  = (nQuads + threads - 1) / threads;  // 4096 blocks, 8 resident/CU
  qc_fused<<<blocks, threads, 0, stream>>>(noise, w, out, nQuads);
}

// Round 4
// 71.517 us; speedup vs baseline: 1.1297x; 1.1297x over previous
//
#include <hip/hip_runtime.h>
#include <math.h>

// Quantum circuit collapses to z_q[b] = x^T K_q y with
//   x = [1, cos(pi*n0), sin(pi*n0)],  y = [1, cos(pi*n1), sin(pi*n1)],
// where K_q (9 floats per wire) depends only on q_weights.
// Derivation: z_q = r^T A_q r, r = kron([c0,s0],[c1,s1]); the Kronecker
// structure folds symmetric A_q into a 3x3 bilinear form over the moment
// vectors [c^2, c s, s^2]; double-angle maps those to [1, C, S]/2.
//
// Structure (harness-verified best, R1): tiny prep kernel computes the 18
// coefficients into d_ws; the streaming kernel is exact-grid, no LDS, no
// barrier, 4 v_sin/v_cos + ~20 FMA per float4 (2 samples) -- memory-bound
// by ~4x, rides the HBM roofline. Fusing prep into the streaming kernel
// was tried twice (R2: 1024-thr, R3: 256-thr) and regressed both times:
// divergent prep + barrier + register fattening cost more than one launch.

struct Cx { float re, im; };
__device__ inline Cx cmul(Cx a, Cx b){ return {a.re*b.re - a.im*b.im, a.re*b.im + a.im*b.re}; }
__device__ inline Cx cmadd2(Cx a, Cx x, Cx b, Cx y){
  Cx p = cmul(a,x), q = cmul(b,y);
  return { p.re + q.re, p.im + q.im };
}

__global__ void qc_prep(const float* __restrict__ w, float* __restrict__ K) {
  if (threadIdx.x != 0) return;

  Cx U[4][4];
  #pragma unroll
  for (int r = 0; r < 4; ++r)
    #pragma unroll
    for (int c = 0; c < 4; ++c)
      U[r][c] = { (r == c) ? 1.f : 0.f, 0.f };

  #pragma unroll
  for (int l = 0; l < 2; ++l) {
    Cx g[2][2][2];  // [wire][i][j]
    #pragma unroll
    for (int q = 0; q < 2; ++q) {
      float phi = w[l*6 + q*3 + 0];
      float th  = w[l*6 + q*3 + 1];
      float om  = w[l*6 + q*3 + 2];
      float st, ct; __sincosf(0.5f*th, &st, &ct);        // native trig: args
      float sp, cp; __sincosf(0.5f*(phi+om), &sp, &cp);  // ~0.1 rad, precision
      float sm, cm; __sincosf(0.5f*(phi-om), &sm, &cm);  // ample at 4e-3 tol
      g[q][0][0] = {  cp*ct, -sp*ct };
      g[q][0][1] = { -cm*st, -sm*st };
      g[q][1][0] = {  cm*st, -sm*st };
      g[q][1][1] = {  cp*ct,  sp*ct };
    }
    // U <- (g0 (x) I) * U   (basis idx = 2*q0 + q1; mixes q0)
    #pragma unroll
    for (int c = 0; c < 4; ++c)
      #pragma unroll
      for (int k = 0; k < 2; ++k) {
        Cx x0 = U[k][c], x1 = U[2+k][c];
        U[k][c]   = cmadd2(g[0][0][0], x0, g[0][0][1], x1);
        U[2+k][c] = cmadd2(g[0][1][0], x0, g[0][1][1], x1);
      }
    // U <- (I (x) g1) * U   (mixes q1)
    #pragma unroll
    for (int c = 0; c < 4; ++c)
      #pragma unroll
      for (int j = 0; j < 2; ++j) {
        Cx x0 = U[2*j][c], x1 = U[2*j+1][c];
        U[2*j][c]   = cmadd2(g[1][0][0], x0, g[1][0][1], x1);
        U[2*j+1][c] = cmadd2(g[1][1][0], x0, g[1][1][1], x1);
      }
    // CNOT(q0->q1): swap rows 2,3 ; CNOT(q1->q0): swap rows 1,3
    #pragma unroll
    for (int c = 0; c < 4; ++c) { Cx t = U[2][c]; U[2][c] = U[3][c]; U[3][c] = t; }
    #pragma unroll
    for (int c = 0; c < 4; ++c) { Cx t = U[1][c]; U[1][c] = U[3][c]; U[3][c] = t; }
  }

  // V = U * D, D = diag(1, -i, -i, -1)
  #pragma unroll
  for (int r = 0; r < 4; ++r) {
    Cx t;
    t = U[r][1]; U[r][1] = {  t.im, -t.re };
    t = U[r][2]; U[r][2] = {  t.im, -t.re };
    t = U[r][3]; U[r][3] = { -t.re, -t.im };
  }

  // A_q[a][b] = sum_r zq[r] * Re( conj(V[r][a]) V[r][b] )   (symmetric)
  const float z0s[4] = { 1.f,  1.f, -1.f, -1.f };
  const float z1s[4] = { 1.f, -1.f,  1.f, -1.f };
  float A[2][16];
  #pragma unroll
  for (int a = 0; a < 4; ++a)
    #pragma unroll
    for (int b = 0; b < 4; ++b) {
      float a0 = 0.f, a1 = 0.f;
      #pragma unroll
      for (int r = 0; r < 4; ++r) {
        float d = U[r][a].re*U[r][b].re + U[r][a].im*U[r][b].im;
        a0 += z0s[r]*d;
        a1 += z1s[r]*d;
      }
      A[0][a*4 + b] = a0;
      A[1][a*4 + b] = a1;
    }

  // Fold Kronecker structure: z = sum_{a,b in 0..2} M[a][b] u_a v_b,
  //   u = [c0^2, c0 s0, s0^2], v likewise (off-diagonals of A appear twice)
  // then basis change [c^2, c s, s^2] = T [1, C, S]^T, K = T^T (M T).
  const float T[3][3] = { {0.5f, 0.5f, 0.f},
                          {0.f,  0.f,  0.5f},
                          {0.5f, -0.5f, 0.f} };
  #pragma unroll
  for (int q = 0; q < 2; ++q) {
    const float* a = A[q];
    float M[9];
    M[0] = a[0];
    M[1] = 2.f*a[1];
    M[2] = a[5];
    M[3] = 2.f*a[2];
    M[4] = 2.f*(a[3]+a[6]);
    M[5] = 2.f*a[7];
    M[6] = a[10];
    M[7] = 2.f*a[11];
    M[8] = a[15];
    float tmp[9];  // tmp = M * T
    #pragma unroll
    for (int r = 0; r < 3; ++r)
      #pragma unroll
      for (int d = 0; d < 3; ++d)
        tmp[r*3+d] = M[r*3+0]*T[0][d] + M[r*3+1]*T[1][d] + M[r*3+2]*T[2][d];
    #pragma unroll
    for (int c = 0; c < 3; ++c)    // K = T^T * tmp
      #pragma unroll
      for (int d = 0; d < 3; ++d)
        K[q*9 + c*3 + d] = T[0][c]*tmp[0*3+d] + T[1][c]*tmp[1*3+d] + T[2][c]*tmp[2*3+d];
  }
}

__device__ inline float evalK(const float* __restrict__ k,
                              float C0, float S0, float C1, float S1) {
  float t0 = fmaf(k[2], S1, fmaf(k[1], C1, k[0]));
  float t1 = fmaf(k[5], S1, fmaf(k[4], C1, k[3]));
  float t2 = fmaf(k[8], S1, fmaf(k[7], C1, k[6]));
  return fmaf(S0, t2, fmaf(C0, t1, t0));
}

__global__ __launch_bounds__(256) void qc_main(const float* __restrict__ noise,
                                               const float* __restrict__ Kg,
                                               float* __restrict__ out,
                                               int nQuads) {
  // 18 uniform coefficients: uniform address -> scalar loads, broadcast free
  float k0[9], k1[9];
  #pragma unroll
  for (int j = 0; j < 9; ++j) { k0[j] = Kg[j]; k1[j] = Kg[9 + j]; }

  const float4* __restrict__ in4  = (const float4*)noise;
  float4* __restrict__ out4 = (float4*)out;

  int i = blockIdx.x * blockDim.x + threadIdx.x;
  if (i >= nQuads) return;

  float4 v = in4[i];   // two samples: (v.x,v.y), (v.z,v.w)

  // v_sin/v_cos take revolutions: cos(pi*n) = v_cos(0.5*n); n in [0,1) needs
  // no range reduction.
  float4 o;
  {
    float C0 = __builtin_amdgcn_cosf(0.5f * v.x);
    float S0 = __builtin_amdgcn_sinf(0.5f * v.x);
    float C1 = __builtin_amdgcn_cosf(0.5f * v.y);
    float S1 = __builtin_amdgcn_sinf(0.5f * v.y);
    o.x = evalK(k0, C0, S0, C1, S1);
    o.y = evalK(k1, C0, S0, C1, S1);
  }
  {
    float C0 = __builtin_amdgcn_cosf(0.5f * v.z);
    float S0 = __builtin_amdgcn_sinf(0.5f * v.z);
    float C1 = __builtin_amdgcn_cosf(0.5f * v.w);
    float S1 = __builtin_amdgcn_sinf(0.5f * v.w);
    o.z = evalK(k0, C0, S0, C1, S1);
    o.w = evalK(k1, C0, S0, C1, S1);
  }
  out4[i] = o;
}

extern "C" void kernel_launch(void* const* d_in, const int* in_sizes, int n_in,
                              void* d_out, int out_size, void* d_ws, size_t ws_size,
                              hipStream_t stream) {
  const float* noise = (const float*)d_in[0];   // [B,2] float32
  const float* w     = (const float*)d_in[1];   // [2,2,3] float32
  float* out         = (float*)d_out;           // [B,2] float32
  float* K           = (float*)d_ws;            // 18 floats

  qc_prep<<<1, 64, 0, stream>>>(w, K);

  int nQuads  = in_sizes[0] / 4;                // (B*2 floats)/4 -> float4 count
  int threads = 256;
  int blocks  = (nQuads + threads - 1) / threads;  // exact grid, 1 float4/thread
  qc_main<<<blocks, threads, 0, stream>>>(noise, K, out, nQuads);
}